// Round 5
// baseline (181.448 us; speedup 1.0000x reference)
//
#include <hip/hip_runtime.h>
#include <stdint.h>

typedef unsigned short u16;
typedef __attribute__((ext_vector_type(8))) short short8;
typedef __attribute__((ext_vector_type(4))) float f32x4;

__device__ __forceinline__ u16 f2bf(float f) {
    union { float f; unsigned int i; } v; v.f = f;
    unsigned int b = v.i;
    return (u16)((b + 0x7FFFu + ((b >> 16) & 1u)) >> 16);
}

// ---------------------------------------------------------------------------
// wprep: weight convert fp32 -> bf16, transposed: Wt[n][k] = W[k][n]
// grid (4,4,4), block 256
// ---------------------------------------------------------------------------
__global__ __launch_bounds__(256) void wprep(
    const float* __restrict__ W0, const float* __restrict__ W1,
    const float* __restrict__ W2, const float* __restrict__ W3,
    u16* __restrict__ T0, u16* __restrict__ T1,
    u16* __restrict__ T2, u16* __restrict__ T3)
{
    const float* W = blockIdx.z == 0 ? W0 : blockIdx.z == 1 ? W1 : blockIdx.z == 2 ? W2 : W3;
    u16*        T  = blockIdx.z == 0 ? T0 : blockIdx.z == 1 ? T1 : blockIdx.z == 2 ? T2 : T3;
    __shared__ u16 ts[64][65];
    int k0 = blockIdx.x * 64, n0 = blockIdx.y * 64;
    int t = threadIdx.x;
    int r = t >> 2, cq = (t & 3) * 16;
    const float4* src = reinterpret_cast<const float4*>(W + (k0 + r) * 256 + n0 + cq);
    for (int u = 0; u < 4; ++u) {
        float4 v = src[u];
        int c = cq + u * 4;
        ts[r][c + 0] = f2bf(v.x); ts[r][c + 1] = f2bf(v.y);
        ts[r][c + 2] = f2bf(v.z); ts[r][c + 3] = f2bf(v.w);
    }
    __syncthreads();
    u16* dst = T + (n0 + r) * 256 + k0 + cq;
    for (int u = 0; u < 16; ++u) dst[u] = ts[cq + u][r];
}

// ---------------------------------------------------------------------------
// Thin-K GEMM core: C[16384,256] = A[16384,256] @ Wt[n][k]^T + bias.
// Block: 4 waves, 128 rows x 64 cols. B staged to LDS ONCE (padded stride
// 264 elems = 528 B), single barrier, then K fully unrolled with A fragments
// loaded directly from global (16 rows x 64B coalesced segments, zero LDS).
// Wave = 32 rows (acc 2x4). No K-loop barriers at all.
// ---------------------------------------------------------------------------
#define KPAD 264

template <bool A_F32, bool F32OUT>
__device__ __forceinline__ void gemm_thin(
    const void* __restrict__ Aptr, const u16* __restrict__ Wt,
    const float* __restrict__ bias, void* __restrict__ Cv,
    int row0, int col0)
{
    __shared__ __align__(16) u16 Bs[64 * KPAD];

    int t = threadIdx.x;
    int lane = t & 63, w = t >> 6;
    int qd = lane >> 4, md = lane & 15;

    // stage B: thread t -> col cj = t>>2, 8 chunks of 8 k-elems
    {
        int cj = t >> 2, c0 = t & 3;
        const uint4* src = reinterpret_cast<const uint4*>(Wt + (size_t)(col0 + cj) * 256);
        uint4* dstrow = reinterpret_cast<uint4*>(&Bs[cj * KPAD]);
#pragma unroll
        for (int s = 0; s < 8; ++s) {
            int c = c0 + s * 4;          // chunk of 8 elems (16 B)
            dstrow[c] = src[c];
        }
    }
    __syncthreads();

    int wr = w * 32;                      // wave's row offset in tile
    f32x4 acc[2][4] = {};

#pragma unroll
    for (int kk = 0; kk < 8; ++kk) {
        int k0 = kk * 32 + qd * 8;
        short8 af[2];
#pragma unroll
        for (int i = 0; i < 2; ++i) {
            size_t row = (size_t)(row0 + wr + i * 16 + md);
            if (A_F32) {
                const float* ap = (const float*)Aptr + row * 256 + k0;
                float4 a0 = *reinterpret_cast<const float4*>(ap);
                float4 a1 = *reinterpret_cast<const float4*>(ap + 4);
                u16 o[8] = {f2bf(a0.x), f2bf(a0.y), f2bf(a0.z), f2bf(a0.w),
                            f2bf(a1.x), f2bf(a1.y), f2bf(a1.z), f2bf(a1.w)};
                af[i] = *reinterpret_cast<const short8*>(o);
            } else {
                af[i] = *reinterpret_cast<const short8*>(
                    (const u16*)Aptr + row * 256 + k0);
            }
        }
        short8 bf[4];
#pragma unroll
        for (int j = 0; j < 4; ++j)
            bf[j] = *reinterpret_cast<const short8*>(
                &Bs[(j * 16 + md) * KPAD + k0]);
#pragma unroll
        for (int i = 0; i < 2; ++i)
#pragma unroll
            for (int j = 0; j < 4; ++j)
                acc[i][j] = __builtin_amdgcn_mfma_f32_16x16x32_bf16(
                    af[i], bf[j], acc[i][j], 0, 0, 0);
    }

#pragma unroll
    for (int i = 0; i < 2; ++i)
#pragma unroll
        for (int j = 0; j < 4; ++j) {
            int col = col0 + j * 16 + md;
            float b = bias[col];
#pragma unroll
            for (int r = 0; r < 4; ++r) {
                int row = row0 + wr + i * 16 + qd * 4 + r;
                if (F32OUT)
                    ((float*)Cv)[(size_t)row * 256 + col] = acc[i][j][r] + b;
                else
                    ((u16*)Cv)[(size_t)row * 256 + col] = f2bf(acc[i][j][r] + b);
            }
        }
}

// gemm_proj: A = fp32 Q or K (direct, converted in-register); 3 outputs via z.
__global__ __launch_bounds__(256) void gemm_proj(
    const float* __restrict__ Q, const float* __restrict__ K,
    const u16* __restrict__ Wtq, const u16* __restrict__ Wtk, const u16* __restrict__ Wtv,
    const float* __restrict__ bq, const float* __restrict__ bk, const float* __restrict__ bv,
    u16* __restrict__ Qh, u16* __restrict__ Kh, u16* __restrict__ Vh)
{
    int z = blockIdx.z;
    const float* A    = (z == 0) ? Q   : K;
    const u16*   Wt   = (z == 0) ? Wtq : (z == 1) ? Wtk : Wtv;
    const float* bias = (z == 0) ? bq  : (z == 1) ? bk  : bv;
    u16*         C    = (z == 0) ? Qh  : (z == 1) ? Kh  : Vh;
    gemm_thin<true, false>(A, Wt, bias, C, blockIdx.x * 128, blockIdx.y * 64);
}

// gemm_out: A = bf16 AVb; fp32 output.
__global__ __launch_bounds__(256) void gemm_out(
    const u16* __restrict__ A, const u16* __restrict__ Wt,
    const float* __restrict__ bias, float* __restrict__ Cout)
{
    gemm_thin<false, true>(A, Wt, bias, Cout, blockIdx.x * 128, blockIdx.y * 64);
}

// ---------------------------------------------------------------------------
// attn: gather attention. One block (256 thr) per 2 rows. (unchanged from R3)
// ---------------------------------------------------------------------------
__global__ __launch_bounds__(256) void attn(
    const u16* __restrict__ Qh, const u16* __restrict__ Kh, const u16* __restrict__ Vh,
    const int* __restrict__ nbr, u16* __restrict__ AVb)
{
    __shared__ float qs[2][256];
    __shared__ float as_[2][256];
    __shared__ int jb[2][32];

    int t = threadIdx.x;
    int row0 = blockIdx.x * 2;
    int b = row0 >> 13;

    {
        int r = t >> 7, c = (t & 127) * 2;
        unsigned int v = *reinterpret_cast<const unsigned int*>(
            Qh + (size_t)(row0 + r) * 256 + c);
        union { unsigned int i; float f; } lo, hi;
        lo.i = v << 16; hi.i = v & 0xffff0000u;
        qs[r][c] = lo.f; qs[r][c + 1] = hi.f;
    }
    if (t < 64) {
        int r = t >> 5, j = t & 31;
        int ji = nbr[(size_t)(row0 + r) * 32 + j];
        jb[r][j] = ((b << 13) + ji) << 9;
    }
    __syncthreads();

    int h = t >> 5, j = t & 31;
#pragma unroll
    for (int r = 0; r < 2; ++r) {
        const char* kp = (const char*)Kh + jb[r][j] + h * 64;
        uint4 kw[4];
        kw[0] = *reinterpret_cast<const uint4*>(kp);
        kw[1] = *reinterpret_cast<const uint4*>(kp + 16);
        kw[2] = *reinterpret_cast<const uint4*>(kp + 32);
        kw[3] = *reinterpret_cast<const uint4*>(kp + 48);
        const float* q = &qs[r][h * 32];
        float e = 0.f;
#pragma unroll
        for (int cq4 = 0; cq4 < 4; ++cq4) {
            unsigned int wds[4] = {kw[cq4].x, kw[cq4].y, kw[cq4].z, kw[cq4].w};
#pragma unroll
            for (int u = 0; u < 4; ++u) {
                union { unsigned int i; float f; } lo, hi;
                lo.i = wds[u] << 16; hi.i = wds[u] & 0xffff0000u;
                e += q[cq4 * 8 + u * 2] * lo.f + q[cq4 * 8 + u * 2 + 1] * hi.f;
            }
        }
        e *= 0.0625f;
        float m = e;
        for (int off = 16; off; off >>= 1) m = fmaxf(m, __shfl_xor(m, off, 32));
        float p = __expf(e - m);
        float s = p;
        for (int off = 16; off; off >>= 1) s += __shfl_xor(s, off, 32);
        as_[r][t] = p / s;
    }
    __syncthreads();

    {
        int r = t >> 7, c = t & 127, hh = c >> 4;
        const float* aw = &as_[r][hh * 32];
        float a0 = 0.f, a1 = 0.f;
#pragma unroll
        for (int jj = 0; jj < 32; ++jj) {
            unsigned int v = *reinterpret_cast<const unsigned int*>(
                (const char*)Vh + jb[r][jj] + c * 4);
            union { unsigned int i; float f; } lo, hi;
            lo.i = v << 16; hi.i = v & 0xffff0000u;
            float wgt = aw[jj];
            a0 += wgt * lo.f; a1 += wgt * hi.f;
        }
        u16 o[2] = {f2bf(a0), f2bf(a1)};
        *reinterpret_cast<unsigned int*>(AVb + (size_t)(row0 + r) * 256 + c * 2) =
            *reinterpret_cast<const unsigned int*>(o);
    }
}

// ---------------------------------------------------------------------------
extern "C" void kernel_launch(void* const* d_in, const int* in_sizes, int n_in,
                              void* d_out, int out_size, void* d_ws, size_t ws_size,
                              hipStream_t stream) {
    const float* Q   = (const float*)d_in[0];
    const float* K   = (const float*)d_in[1];
    const int*   nbr = (const int*)d_in[2];
    const float* Wq  = (const float*)d_in[3];
    const float* bq  = (const float*)d_in[4];
    const float* Wk  = (const float*)d_in[5];
    const float* bk  = (const float*)d_in[6];
    const float* Wv  = (const float*)d_in[7];
    const float* bv  = (const float*)d_in[8];
    const float* Wo  = (const float*)d_in[9];
    const float* bo  = (const float*)d_in[10];
    float* out = (float*)d_out;

    char* ws = (char*)d_ws;
    size_t off = 0;
    auto alloc = [&](size_t bytes) -> void* {
        void* p = ws + off;
        off += (bytes + 255) & ~(size_t)255;
        return p;
    };
    const size_t MN = 16384;
    u16* Wtq = (u16*)alloc(256 * 256 * 2);
    u16* Wtk = (u16*)alloc(256 * 256 * 2);
    u16* Wtv = (u16*)alloc(256 * 256 * 2);
    u16* Wto = (u16*)alloc(256 * 256 * 2);
    u16* Qh  = (u16*)alloc(MN * 256 * 2);
    u16* Kh  = (u16*)alloc(MN * 256 * 2);
    u16* Vh  = (u16*)alloc(MN * 256 * 2);
    u16* AVb = (u16*)alloc(MN * 256 * 2);

    wprep<<<dim3(4, 4, 4), 256, 0, stream>>>(Wq, Wk, Wv, Wo, Wtq, Wtk, Wtv, Wto);
    gemm_proj<<<dim3(128, 4, 3), 256, 0, stream>>>(Q, K, Wtq, Wtk, Wtv,
                                                   bq, bk, bv, Qh, Kh, Vh);
    attn<<<dim3(8192), 256, 0, stream>>>(Qh, Kh, Vh, nbr, AVb);
    gemm_out<<<dim3(128, 4), 256, 0, stream>>>(AVb, Wto, bo, out);
}

// Round 6
// 171.004 us; speedup vs baseline: 1.0611x; 1.0611x over previous
//
#include <hip/hip_runtime.h>
#include <hip/hip_bf16.h>
#include <stdint.h>

typedef unsigned short u16;
typedef __attribute__((ext_vector_type(8))) short short8;
typedef __attribute__((ext_vector_type(4))) float f32x4;

__device__ __forceinline__ u16 f2bf(float f) {
    union { float f; unsigned int i; } v; v.f = f;
    unsigned int b = v.i;
    return (u16)((b + 0x7FFFu + ((b >> 16) & 1u)) >> 16);
}

// pack 8 fp32 -> 8 bf16 (RNE) using packed HIP intrinsic
__device__ __forceinline__ short8 cvt8(float4 a, float4 b) {
    union { __hip_bfloat162 h[4]; short8 s; } u;
    u.h[0] = __float22bfloat162_rn(make_float2(a.x, a.y));
    u.h[1] = __float22bfloat162_rn(make_float2(a.z, a.w));
    u.h[2] = __float22bfloat162_rn(make_float2(b.x, b.y));
    u.h[3] = __float22bfloat162_rn(make_float2(b.z, b.w));
    return u.s;
}

// async global->LDS, 16B/lane: per-lane GLOBAL addr, wave-uniform LDS base.
typedef const __attribute__((address_space(1))) void* as1cv;
typedef __attribute__((address_space(3))) void* as3v;
__device__ __forceinline__ void gload16(const void* g, void* l) {
    __builtin_amdgcn_global_load_lds((as1cv)g, (as3v)l, 16, 0, 0);
}

// ---------------------------------------------------------------------------
// wprep: weight convert fp32 -> bf16, transposed: Wt[n][k] = W[k][n]
// ---------------------------------------------------------------------------
__global__ __launch_bounds__(256) void wprep(
    const float* __restrict__ W0, const float* __restrict__ W1,
    const float* __restrict__ W2, const float* __restrict__ W3,
    u16* __restrict__ T0, u16* __restrict__ T1,
    u16* __restrict__ T2, u16* __restrict__ T3)
{
    const float* W = blockIdx.z == 0 ? W0 : blockIdx.z == 1 ? W1 : blockIdx.z == 2 ? W2 : W3;
    u16*        T  = blockIdx.z == 0 ? T0 : blockIdx.z == 1 ? T1 : blockIdx.z == 2 ? T2 : T3;
    __shared__ u16 ts[64][65];
    int k0 = blockIdx.x * 64, n0 = blockIdx.y * 64;
    int t = threadIdx.x;
    int r = t >> 2, cq = (t & 3) * 16;
    const float4* src = reinterpret_cast<const float4*>(W + (k0 + r) * 256 + n0 + cq);
    for (int u = 0; u < 4; ++u) {
        float4 v = src[u];
        int c = cq + u * 4;
        ts[r][c + 0] = f2bf(v.x); ts[r][c + 1] = f2bf(v.y);
        ts[r][c + 2] = f2bf(v.z); ts[r][c + 3] = f2bf(v.w);
    }
    __syncthreads();
    u16* dst = T + (n0 + r) * 256 + k0 + cq;
    for (int u = 0; u < 16; ++u) dst[u] = ts[cq + u][r];
}

// ---------------------------------------------------------------------------
// gemm_proj: C_bf16[16384,256] = cvt(A_fp32) @ Wt^T + bias.
// 128x128 tile, BK=64. A staged as *fp32* via gload16 (32 KB), B bf16 (16 KB).
// XOR-swizzled LDS slots (16B granules): slot c holds global granule
// c ^ (row & mask) -> conflict-free ds_read_b128 without padding.
// Convert fp32->bf16 at fragment read (packed RNE). grid (128,2,3).
// ---------------------------------------------------------------------------
__global__ __launch_bounds__(256) void gemm_proj(
    const float* __restrict__ Q, const float* __restrict__ K,
    const u16* __restrict__ Wtq, const u16* __restrict__ Wtk, const u16* __restrict__ Wtv,
    const float* __restrict__ bq, const float* __restrict__ bk, const float* __restrict__ bv,
    u16* __restrict__ Qh, u16* __restrict__ Kh, u16* __restrict__ Vh)
{
    int z = blockIdx.z;
    const float* Af   = (z == 0) ? Q   : K;
    const u16*   Wt   = (z == 0) ? Wtq : (z == 1) ? Wtk : Wtv;
    const float* bias = (z == 0) ? bq  : (z == 1) ? bk  : bv;
    u16*         C    = (z == 0) ? Qh  : (z == 1) ? Kh  : Vh;

    __shared__ float Asf[128 * 64];   // 32 KB, 16 slots(16B)/row
    __shared__ u16   Bs[128 * 64];    // 16 KB, 8 slots/row

    int t = threadIdx.x;
    int lane = t & 63, w = t >> 6;
    int row0 = blockIdx.x * 128, col0 = blockIdx.y * 128;
    int wr = (w >> 1) * 64, wc = (w & 1) * 64;
    int qd = lane >> 4, md = lane & 15;

    f32x4 acc[4][4] = {};

    for (int kt = 0; kt < 256; kt += 64) {
        // A: 32 KB = 32 chunks of 1 KB; chunk = w*8+u; slot s = chunk*64+lane
#pragma unroll
        for (int u = 0; u < 8; ++u) {
            int chunk = w * 8 + u;
            int s = chunk * 64 + lane;
            int r = s >> 4, c = s & 15;
            gload16(Af + (size_t)(row0 + r) * 256 + kt + ((c ^ (r & 15)) * 4),
                    (char*)Asf + chunk * 1024);
        }
        // B: 16 KB = 16 chunks; chunk = w*4+u
#pragma unroll
        for (int u = 0; u < 4; ++u) {
            int chunk = w * 4 + u;
            int s = chunk * 64 + lane;
            int r = s >> 3, c = s & 7;
            gload16(Wt + (size_t)(col0 + r) * 256 + kt + ((c ^ (r & 7)) * 8),
                    (char*)Bs + chunk * 1024);
        }
        __syncthreads();
#pragma unroll
        for (int ks = 0; ks < 64; ks += 32) {
            short8 af[4], bf[4];
#pragma unroll
            for (int i = 0; i < 4; ++i) {
                int ar = wr + i * 16 + md;
                int c0 = (ks >> 2) + qd * 2;     // fp32 16B-slot index
                int x = ar & 15;
                float4 fa0 = reinterpret_cast<const float4*>(Asf)[ar * 16 + (c0 ^ x)];
                float4 fa1 = reinterpret_cast<const float4*>(Asf)[ar * 16 + ((c0 + 1) ^ x)];
                af[i] = cvt8(fa0, fa1);
            }
#pragma unroll
            for (int j = 0; j < 4; ++j) {
                int br = wc + j * 16 + md;
                int slot = ((ks >> 3) + qd) ^ (br & 7);
                bf[j] = reinterpret_cast<const short8*>(Bs)[br * 8 + slot];
            }
#pragma unroll
            for (int i = 0; i < 4; ++i)
#pragma unroll
                for (int j = 0; j < 4; ++j)
                    acc[i][j] = __builtin_amdgcn_mfma_f32_16x16x32_bf16(
                        af[i], bf[j], acc[i][j], 0, 0, 0);
        }
        __syncthreads();
    }

#pragma unroll
    for (int i = 0; i < 4; ++i)
#pragma unroll
        for (int j = 0; j < 4; ++j) {
            int col = col0 + wc + j * 16 + md;
            float b = bias[col];
#pragma unroll
            for (int r = 0; r < 4; ++r) {
                int row = row0 + wr + i * 16 + qd * 4 + r;
                C[(size_t)row * 256 + col] = f2bf(acc[i][j][r] + b);
            }
        }
}

// ---------------------------------------------------------------------------
// gemm_out: f32 C = bf16 A @ Wt^T + bias. 64x128 tile, BK=64, 4 waves of
// 32r x 64c (acc 2x4). XOR-swizzled LDS. grid (256,2) = 512 blocks, 24 KB.
// ---------------------------------------------------------------------------
__global__ __launch_bounds__(256) void gemm_out(
    const u16* __restrict__ Ab, const u16* __restrict__ Wt,
    const float* __restrict__ bias, float* __restrict__ Cout)
{
    __shared__ u16 As[64 * 64];    // 8 KB, 8 chunks
    __shared__ u16 Bs[128 * 64];   // 16 KB, 16 chunks

    int t = threadIdx.x;
    int lane = t & 63, w = t >> 6;
    int row0 = blockIdx.x * 64, col0 = blockIdx.y * 128;
    int wr = (w >> 1) * 32, wc = (w & 1) * 64;
    int qd = lane >> 4, md = lane & 15;

    f32x4 acc[2][4] = {};

    for (int kt = 0; kt < 256; kt += 64) {
#pragma unroll
        for (int u = 0; u < 2; ++u) {
            int chunk = w * 2 + u;
            int s = chunk * 64 + lane;
            int r = s >> 3, c = s & 7;
            gload16(Ab + (size_t)(row0 + r) * 256 + kt + ((c ^ (r & 7)) * 8),
                    (char*)As + chunk * 1024);
        }
#pragma unroll
        for (int u = 0; u < 4; ++u) {
            int chunk = w * 4 + u;
            int s = chunk * 64 + lane;
            int r = s >> 3, c = s & 7;
            gload16(Wt + (size_t)(col0 + r) * 256 + kt + ((c ^ (r & 7)) * 8),
                    (char*)Bs + chunk * 1024);
        }
        __syncthreads();
#pragma unroll
        for (int ks = 0; ks < 64; ks += 32) {
            short8 af[2], bf[4];
#pragma unroll
            for (int i = 0; i < 2; ++i) {
                int ar = wr + i * 16 + md;
                int slot = ((ks >> 3) + qd) ^ (ar & 7);
                af[i] = reinterpret_cast<const short8*>(As)[ar * 8 + slot];
            }
#pragma unroll
            for (int j = 0; j < 4; ++j) {
                int br = wc + j * 16 + md;
                int slot = ((ks >> 3) + qd) ^ (br & 7);
                bf[j] = reinterpret_cast<const short8*>(Bs)[br * 8 + slot];
            }
#pragma unroll
            for (int i = 0; i < 2; ++i)
#pragma unroll
                for (int j = 0; j < 4; ++j)
                    acc[i][j] = __builtin_amdgcn_mfma_f32_16x16x32_bf16(
                        af[i], bf[j], acc[i][j], 0, 0, 0);
        }
        __syncthreads();
    }

#pragma unroll
    for (int i = 0; i < 2; ++i)
#pragma unroll
        for (int j = 0; j < 4; ++j) {
            int col = col0 + wc + j * 16 + md;
            float b = bias[col];
#pragma unroll
            for (int r = 0; r < 4; ++r) {
                int row = row0 + wr + i * 16 + qd * 4 + r;
                Cout[(size_t)row * 256 + col] = acc[i][j][r] + b;
            }
        }
}

// ---------------------------------------------------------------------------
// attn: one block (256 thr) per 4 rows. Scores: thread->(h,j), loop 4 rows.
// AV: 64 thr/row, dwordx2 loads, neighbour base scalarized (readfirstlane).
// ---------------------------------------------------------------------------
__global__ __launch_bounds__(256) void attn(
    const u16* __restrict__ Qh, const u16* __restrict__ Kh, const u16* __restrict__ Vh,
    const int* __restrict__ nbr, u16* __restrict__ AVb)
{
    __shared__ float qs[4][256];
    __shared__ float as_[4][256];
    __shared__ int jb[4][32];

    int t = threadIdx.x;
    int row0 = blockIdx.x * 4;
    int b = row0 >> 13;

    // Q: 4 rows x 128 dwords, 2 per thread
#pragma unroll
    for (int rr = 0; rr < 2; ++rr) {
        int idx = rr * 256 + t;
        int r = idx >> 7, c = (idx & 127) * 2;
        unsigned int v = *reinterpret_cast<const unsigned int*>(
            Qh + (size_t)(row0 + r) * 256 + c);
        union { unsigned int i; float f; } lo, hi;
        lo.i = v << 16; hi.i = v & 0xffff0000u;
        qs[r][c] = lo.f; qs[r][c + 1] = hi.f;
    }
    if (t < 128) {
        int r = t >> 5, j = t & 31;
        int ji = nbr[(size_t)(row0 + r) * 32 + j];
        jb[r][j] = ((b << 13) + ji) << 9;   // row byte offset
    }
    __syncthreads();

    // scores
    int h = t >> 5, j = t & 31;
#pragma unroll
    for (int r = 0; r < 4; ++r) {
        const char* kp = (const char*)Kh + jb[r][j] + h * 64;
        uint4 kw[4];
        kw[0] = *reinterpret_cast<const uint4*>(kp);
        kw[1] = *reinterpret_cast<const uint4*>(kp + 16);
        kw[2] = *reinterpret_cast<const uint4*>(kp + 32);
        kw[3] = *reinterpret_cast<const uint4*>(kp + 48);
        const float* q = &qs[r][h * 32];
        float e = 0.f;
#pragma unroll
        for (int cq4 = 0; cq4 < 4; ++cq4) {
            unsigned int wds[4] = {kw[cq4].x, kw[cq4].y, kw[cq4].z, kw[cq4].w};
#pragma unroll
            for (int u = 0; u < 4; ++u) {
                union { unsigned int i; float f; } lo, hi;
                lo.i = wds[u] << 16; hi.i = wds[u] & 0xffff0000u;
                e += q[cq4 * 8 + u * 2] * lo.f + q[cq4 * 8 + u * 2 + 1] * hi.f;
            }
        }
        e *= 0.0625f;
        float m = e;
        for (int off = 16; off; off >>= 1) m = fmaxf(m, __shfl_xor(m, off, 32));
        float p = __expf(e - m);
        float s = p;
        for (int off = 16; off; off >>= 1) s += __shfl_xor(s, off, 32);
        as_[r][t] = p / s;
    }
    __syncthreads();

    // AV: r = t>>6 (wave-uniform), 4 channels at c2*4
    {
        int r = t >> 6, c2 = t & 63;
        int hh = c2 >> 3;                  // head of channel c2*4
        float wv[32];
#pragma unroll
        for (int u = 0; u < 8; ++u)
            *reinterpret_cast<float4*>(&wv[u * 4]) =
                *reinterpret_cast<const float4*>(&as_[r][hh * 32 + u * 4]);
        float a0 = 0.f, a1 = 0.f, a2 = 0.f, a3 = 0.f;
#pragma unroll
        for (int jj = 0; jj < 32; ++jj) {
            int off = __builtin_amdgcn_readfirstlane(jb[r][jj]);
            uint2 v = *reinterpret_cast<const uint2*>(
                (const char*)Vh + off + c2 * 8);
            union { unsigned int i; float f; } l0, h0, l1, h1;
            l0.i = v.x << 16; h0.i = v.x & 0xffff0000u;
            l1.i = v.y << 16; h1.i = v.y & 0xffff0000u;
            float wgt = wv[jj];
            a0 += wgt * l0.f; a1 += wgt * h0.f;
            a2 += wgt * l1.f; a3 += wgt * h1.f;
        }
        u16 o[4] = {f2bf(a0), f2bf(a1), f2bf(a2), f2bf(a3)};
        *reinterpret_cast<uint2*>(AVb + (size_t)(row0 + r) * 256 + c2 * 4) =
            *reinterpret_cast<const uint2*>(o);
    }
}

// ---------------------------------------------------------------------------
extern "C" void kernel_launch(void* const* d_in, const int* in_sizes, int n_in,
                              void* d_out, int out_size, void* d_ws, size_t ws_size,
                              hipStream_t stream) {
    const float* Q   = (const float*)d_in[0];
    const float* K   = (const float*)d_in[1];
    const int*   nbr = (const int*)d_in[2];
    const float* Wq  = (const float*)d_in[3];
    const float* bq  = (const float*)d_in[4];
    const float* Wk  = (const float*)d_in[5];
    const float* bk  = (const float*)d_in[6];
    const float* Wv  = (const float*)d_in[7];
    const float* bv  = (const float*)d_in[8];
    const float* Wo  = (const float*)d_in[9];
    const float* bo  = (const float*)d_in[10];
    float* out = (float*)d_out;

    char* ws = (char*)d_ws;
    size_t off = 0;
    auto alloc = [&](size_t bytes) -> void* {
        void* p = ws + off;
        off += (bytes + 255) & ~(size_t)255;
        return p;
    };
    const size_t MN = 16384;
    u16* Wtq = (u16*)alloc(256 * 256 * 2);
    u16* Wtk = (u16*)alloc(256 * 256 * 2);
    u16* Wtv = (u16*)alloc(256 * 256 * 2);
    u16* Wto = (u16*)alloc(256 * 256 * 2);
    u16* Qh  = (u16*)alloc(MN * 256 * 2);
    u16* Kh  = (u16*)alloc(MN * 256 * 2);
    u16* Vh  = (u16*)alloc(MN * 256 * 2);
    u16* AVb = (u16*)alloc(MN * 256 * 2);

    wprep<<<dim3(4, 4, 4), 256, 0, stream>>>(Wq, Wk, Wv, Wo, Wtq, Wtk, Wtv, Wto);
    gemm_proj<<<dim3(128, 2, 3), 256, 0, stream>>>(Q, K, Wtq, Wtk, Wtv,
                                                   bq, bk, bv, Qh, Kh, Vh);
    attn<<<dim3(4096), 256, 0, stream>>>(Qh, Kh, Vh, nbr, AVb);
    gemm_out<<<dim3(256, 2), 256, 0, stream>>>(AVb, Wto, bo, out);
}

// Round 7
// 161.456 us; speedup vs baseline: 1.1238x; 1.0591x over previous
//
#include <hip/hip_runtime.h>
#include <hip/hip_bf16.h>
#include <stdint.h>

typedef unsigned short u16;
typedef __attribute__((ext_vector_type(8))) short short8;
typedef __attribute__((ext_vector_type(4))) float f32x4;

__device__ __forceinline__ u16 f2bf(float f) {
    union { float f; unsigned int i; } v; v.f = f;
    unsigned int b = v.i;
    return (u16)((b + 0x7FFFu + ((b >> 16) & 1u)) >> 16);
}

__device__ __forceinline__ short8 cvt8(float4 a, float4 b) {
    union { __hip_bfloat162 h[4]; short8 s; } u;
    u.h[0] = __float22bfloat162_rn(make_float2(a.x, a.y));
    u.h[1] = __float22bfloat162_rn(make_float2(a.z, a.w));
    u.h[2] = __float22bfloat162_rn(make_float2(b.x, b.y));
    u.h[3] = __float22bfloat162_rn(make_float2(b.z, b.w));
    return u.s;
}

typedef const __attribute__((address_space(1))) void* as1cv;
typedef __attribute__((address_space(3))) void* as3v;
__device__ __forceinline__ void gload16(const void* g, void* l) {
    __builtin_amdgcn_global_load_lds((as1cv)g, (as3v)l, 16, 0, 0);
}

// unpack one dword (2 bf16) into two floats
__device__ __forceinline__ void up2(unsigned int v, float& lo, float& hi) {
    union { unsigned int i; float f; } a, b;
    a.i = v << 16; b.i = v & 0xffff0000u;
    lo = a.f; hi = b.f;
}

// ---------------------------------------------------------------------------
// wprep: weight convert fp32 -> bf16, transposed: Wt[n][k] = W[k][n]
// ---------------------------------------------------------------------------
__global__ __launch_bounds__(256) void wprep(
    const float* __restrict__ W0, const float* __restrict__ W1,
    const float* __restrict__ W2, const float* __restrict__ W3,
    u16* __restrict__ T0, u16* __restrict__ T1,
    u16* __restrict__ T2, u16* __restrict__ T3)
{
    const float* W = blockIdx.z == 0 ? W0 : blockIdx.z == 1 ? W1 : blockIdx.z == 2 ? W2 : W3;
    u16*        T  = blockIdx.z == 0 ? T0 : blockIdx.z == 1 ? T1 : blockIdx.z == 2 ? T2 : T3;
    __shared__ u16 ts[64][65];
    int k0 = blockIdx.x * 64, n0 = blockIdx.y * 64;
    int t = threadIdx.x;
    int r = t >> 2, cq = (t & 3) * 16;
    const float4* src = reinterpret_cast<const float4*>(W + (k0 + r) * 256 + n0 + cq);
    for (int u = 0; u < 4; ++u) {
        float4 v = src[u];
        int c = cq + u * 4;
        ts[r][c + 0] = f2bf(v.x); ts[r][c + 1] = f2bf(v.y);
        ts[r][c + 2] = f2bf(v.z); ts[r][c + 3] = f2bf(v.w);
    }
    __syncthreads();
    u16* dst = T + (n0 + r) * 256 + k0 + cq;
    for (int u = 0; u < 16; ++u) dst[u] = ts[cq + u][r];
}

// ---------------------------------------------------------------------------
// gemm_proj: C_bf16 = cvt(A_fp32) @ Wt^T + bias. 128x128, BK=64,
// XOR-swizzled LDS, global_load_lds staging. (unchanged from R6)
// ---------------------------------------------------------------------------
__global__ __launch_bounds__(256) void gemm_proj(
    const float* __restrict__ Q, const float* __restrict__ K,
    const u16* __restrict__ Wtq, const u16* __restrict__ Wtk, const u16* __restrict__ Wtv,
    const float* __restrict__ bq, const float* __restrict__ bk, const float* __restrict__ bv,
    u16* __restrict__ Qh, u16* __restrict__ Kh, u16* __restrict__ Vh)
{
    int z = blockIdx.z;
    const float* Af   = (z == 0) ? Q   : K;
    const u16*   Wt   = (z == 0) ? Wtq : (z == 1) ? Wtk : Wtv;
    const float* bias = (z == 0) ? bq  : (z == 1) ? bk  : bv;
    u16*         C    = (z == 0) ? Qh  : (z == 1) ? Kh  : Vh;

    __shared__ float Asf[128 * 64];
    __shared__ u16   Bs[128 * 64];

    int t = threadIdx.x;
    int lane = t & 63, w = t >> 6;
    int row0 = blockIdx.x * 128, col0 = blockIdx.y * 128;
    int wr = (w >> 1) * 64, wc = (w & 1) * 64;
    int qd = lane >> 4, md = lane & 15;

    f32x4 acc[4][4] = {};

    for (int kt = 0; kt < 256; kt += 64) {
#pragma unroll
        for (int u = 0; u < 8; ++u) {
            int chunk = w * 8 + u;
            int s = chunk * 64 + lane;
            int r = s >> 4, c = s & 15;
            gload16(Af + (size_t)(row0 + r) * 256 + kt + ((c ^ (r & 15)) * 4),
                    (char*)Asf + chunk * 1024);
        }
#pragma unroll
        for (int u = 0; u < 4; ++u) {
            int chunk = w * 4 + u;
            int s = chunk * 64 + lane;
            int r = s >> 3, c = s & 7;
            gload16(Wt + (size_t)(col0 + r) * 256 + kt + ((c ^ (r & 7)) * 8),
                    (char*)Bs + chunk * 1024);
        }
        __syncthreads();
#pragma unroll
        for (int ks = 0; ks < 64; ks += 32) {
            short8 af[4], bf[4];
#pragma unroll
            for (int i = 0; i < 4; ++i) {
                int ar = wr + i * 16 + md;
                int c0 = (ks >> 2) + qd * 2;
                int x = ar & 15;
                float4 fa0 = reinterpret_cast<const float4*>(Asf)[ar * 16 + (c0 ^ x)];
                float4 fa1 = reinterpret_cast<const float4*>(Asf)[ar * 16 + ((c0 + 1) ^ x)];
                af[i] = cvt8(fa0, fa1);
            }
#pragma unroll
            for (int j = 0; j < 4; ++j) {
                int br = wc + j * 16 + md;
                int slot = ((ks >> 3) + qd) ^ (br & 7);
                bf[j] = reinterpret_cast<const short8*>(Bs)[br * 8 + slot];
            }
#pragma unroll
            for (int i = 0; i < 4; ++i)
#pragma unroll
                for (int j = 0; j < 4; ++j)
                    acc[i][j] = __builtin_amdgcn_mfma_f32_16x16x32_bf16(
                        af[i], bf[j], acc[i][j], 0, 0, 0);
        }
        __syncthreads();
    }

#pragma unroll
    for (int i = 0; i < 4; ++i)
#pragma unroll
        for (int j = 0; j < 4; ++j) {
            int col = col0 + wc + j * 16 + md;
            float b = bias[col];
#pragma unroll
            for (int r = 0; r < 4; ++r) {
                int row = row0 + wr + i * 16 + qd * 4 + r;
                C[(size_t)row * 256 + col] = f2bf(acc[i][j][r] + b);
            }
        }
}

// ---------------------------------------------------------------------------
// gemm_out: f32 C = bf16 A @ Wt^T + bias. 64x128 tile. (unchanged from R6)
// ---------------------------------------------------------------------------
__global__ __launch_bounds__(256) void gemm_out(
    const u16* __restrict__ Ab, const u16* __restrict__ Wt,
    const float* __restrict__ bias, float* __restrict__ Cout)
{
    __shared__ u16 As[64 * 64];
    __shared__ u16 Bs[128 * 64];

    int t = threadIdx.x;
    int lane = t & 63, w = t >> 6;
    int row0 = blockIdx.x * 64, col0 = blockIdx.y * 128;
    int wr = (w >> 1) * 32, wc = (w & 1) * 64;
    int qd = lane >> 4, md = lane & 15;

    f32x4 acc[2][4] = {};

    for (int kt = 0; kt < 256; kt += 64) {
#pragma unroll
        for (int u = 0; u < 2; ++u) {
            int chunk = w * 2 + u;
            int s = chunk * 64 + lane;
            int r = s >> 3, c = s & 7;
            gload16(Ab + (size_t)(row0 + r) * 256 + kt + ((c ^ (r & 7)) * 8),
                    (char*)As + chunk * 1024);
        }
#pragma unroll
        for (int u = 0; u < 4; ++u) {
            int chunk = w * 4 + u;
            int s = chunk * 64 + lane;
            int r = s >> 3, c = s & 7;
            gload16(Wt + (size_t)(col0 + r) * 256 + kt + ((c ^ (r & 7)) * 8),
                    (char*)Bs + chunk * 1024);
        }
        __syncthreads();
#pragma unroll
        for (int ks = 0; ks < 64; ks += 32) {
            short8 af[2], bf[4];
#pragma unroll
            for (int i = 0; i < 2; ++i) {
                int ar = wr + i * 16 + md;
                int slot = ((ks >> 3) + qd) ^ (ar & 7);
                af[i] = reinterpret_cast<const short8*>(As)[ar * 8 + slot];
            }
#pragma unroll
            for (int j = 0; j < 4; ++j) {
                int br = wc + j * 16 + md;
                int slot = ((ks >> 3) + qd) ^ (br & 7);
                bf[j] = reinterpret_cast<const short8*>(Bs)[br * 8 + slot];
            }
#pragma unroll
            for (int i = 0; i < 2; ++i)
#pragma unroll
                for (int j = 0; j < 4; ++j)
                    acc[i][j] = __builtin_amdgcn_mfma_f32_16x16x32_bf16(
                        af[i], bf[j], acc[i][j], 0, 0, 0);
        }
        __syncthreads();
    }

#pragma unroll
    for (int i = 0; i < 2; ++i)
#pragma unroll
        for (int j = 0; j < 4; ++j) {
            int col = col0 + wc + j * 16 + md;
            float b = bias[col];
#pragma unroll
            for (int r = 0; r < 4; ++r) {
                int row = row0 + wr + i * 16 + qd * 4 + r;
                Cout[(size_t)row * 256 + col] = acc[i][j][r] + b;
            }
        }
}

// ---------------------------------------------------------------------------
// attn v4: ONE WAVE PER ROW, zero barriers, fully-coalesced gathers.
// Lane = (chunk c8 = lane&31 -> channels 8*c8..+8, nbr-half jh = lane>>5).
// Score: for 16 nbrs, one dwordx4 K load/lane (wave inst = 2 full contiguous
// 512B rows); partial dot reduced over the 4 chunk-lanes of a head
// (shfl_xor 1,2). Softmax in registers (xor-32 combine). Weights land in
// exactly the lanes that need them for AV -> zero LDS round-trip. AV loads
// mirror the K pattern; cross-half combine via shfl_xor 32.
// LDS: 512 B of neighbour offsets. Block = 4 independent waves.
// ---------------------------------------------------------------------------
__global__ __launch_bounds__(256) void attn(
    const u16* __restrict__ Qh, const u16* __restrict__ Kh, const u16* __restrict__ Vh,
    const int* __restrict__ nbr, u16* __restrict__ AVb)
{
    __shared__ int jbs[4][32];   // neighbour row element-offsets, per wave

    int t = threadIdx.x;
    int w = t >> 6, lane = t & 63;
    int row = blockIdx.x * 4 + w;
    int b = row >> 13;
    int bbase = b << 13;

    int c8 = lane & 31;          // channel chunk: channels [c8*8, c8*8+8)
    int jh = lane >> 5;          // neighbour half: nbrs [jh*16, jh*16+16)

    // stage neighbour offsets (wave-local, no barrier needed)
    if (lane < 32) {
        int ji = nbr[(size_t)row * 32 + lane];
        jbs[w][lane] = (bbase + ji) * 256;
    }

    // Q chunk for this lane (8 ch), unpacked to f32
    float qf[8];
    {
        uint4 qw = *reinterpret_cast<const uint4*>(Qh + (size_t)row * 256 + c8 * 8);
        up2(qw.x, qf[0], qf[1]); up2(qw.y, qf[2], qf[3]);
        up2(qw.z, qf[4], qf[5]); up2(qw.w, qf[6], qf[7]);
    }

    // ---- scores ----
    float e16[16];
#pragma unroll
    for (int jj = 0; jj < 16; ++jj) {
        int koff = jbs[w][jh * 16 + jj];
        uint4 kw = *reinterpret_cast<const uint4*>(Kh + (size_t)koff + c8 * 8);
        float k0, k1;
        float p = 0.f;
        up2(kw.x, k0, k1); p = fmaf(qf[0], k0, p); p = fmaf(qf[1], k1, p);
        up2(kw.y, k0, k1); p = fmaf(qf[2], k0, p); p = fmaf(qf[3], k1, p);
        up2(kw.z, k0, k1); p = fmaf(qf[4], k0, p); p = fmaf(qf[5], k1, p);
        up2(kw.w, k0, k1); p = fmaf(qf[6], k0, p); p = fmaf(qf[7], k1, p);
        // reduce over the 4 chunk-lanes of this head (c8 aligned groups of 4)
        p += __shfl_xor(p, 1);
        p += __shfl_xor(p, 2);
        e16[jj] = p * 0.0625f;   // 1/sqrt(256)
    }

    // ---- softmax over 32 nbrs (16 local + xor-32 half) ----
    float m = e16[0];
#pragma unroll
    for (int jj = 1; jj < 16; ++jj) m = fmaxf(m, e16[jj]);
    m = fmaxf(m, __shfl_xor(m, 32));
    float s = 0.f;
#pragma unroll
    for (int jj = 0; jj < 16; ++jj) { e16[jj] = __expf(e16[jj] - m); s += e16[jj]; }
    s += __shfl_xor(s, 32);
    float rs = 1.0f / s;
#pragma unroll
    for (int jj = 0; jj < 16; ++jj) e16[jj] *= rs;

    // ---- AV ----
    float acc[8] = {};
#pragma unroll
    for (int jj = 0; jj < 16; ++jj) {
        int voff = jbs[w][jh * 16 + jj];
        uint4 vv = *reinterpret_cast<const uint4*>(Vh + (size_t)voff + c8 * 8);
        float v0, v1;
        float wgt = e16[jj];
        up2(vv.x, v0, v1); acc[0] = fmaf(wgt, v0, acc[0]); acc[1] = fmaf(wgt, v1, acc[1]);
        up2(vv.y, v0, v1); acc[2] = fmaf(wgt, v0, acc[2]); acc[3] = fmaf(wgt, v1, acc[3]);
        up2(vv.z, v0, v1); acc[4] = fmaf(wgt, v0, acc[4]); acc[5] = fmaf(wgt, v1, acc[5]);
        up2(vv.w, v0, v1); acc[6] = fmaf(wgt, v0, acc[6]); acc[7] = fmaf(wgt, v1, acc[7]);
    }
    // combine the two nbr-halves
#pragma unroll
    for (int u = 0; u < 8; ++u) acc[u] += __shfl_xor(acc[u], 32);

    if (lane < 32) {
        union { __hip_bfloat162 h[4]; uint4 u4; } o;
        o.h[0] = __float22bfloat162_rn(make_float2(acc[0], acc[1]));
        o.h[1] = __float22bfloat162_rn(make_float2(acc[2], acc[3]));
        o.h[2] = __float22bfloat162_rn(make_float2(acc[4], acc[5]));
        o.h[3] = __float22bfloat162_rn(make_float2(acc[6], acc[7]));
        *reinterpret_cast<uint4*>(AVb + (size_t)row * 256 + c8 * 8) = o.u4;
    }
}

// ---------------------------------------------------------------------------
extern "C" void kernel_launch(void* const* d_in, const int* in_sizes, int n_in,
                              void* d_out, int out_size, void* d_ws, size_t ws_size,
                              hipStream_t stream) {
    const float* Q   = (const float*)d_in[0];
    const float* K   = (const float*)d_in[1];
    const int*   nbr = (const int*)d_in[2];
    const float* Wq  = (const float*)d_in[3];
    const float* bq  = (const float*)d_in[4];
    const float* Wk  = (const float*)d_in[5];
    const float* bk  = (const float*)d_in[6];
    const float* Wv  = (const float*)d_in[7];
    const float* bv  = (const float*)d_in[8];
    const float* Wo  = (const float*)d_in[9];
    const float* bo  = (const float*)d_in[10];
    float* out = (float*)d_out;

    char* ws = (char*)d_ws;
    size_t off = 0;
    auto alloc = [&](size_t bytes) -> void* {
        void* p = ws + off;
        off += (bytes + 255) & ~(size_t)255;
        return p;
    };
    const size_t MN = 16384;
    u16* Wtq = (u16*)alloc(256 * 256 * 2);
    u16* Wtk = (u16*)alloc(256 * 256 * 2);
    u16* Wtv = (u16*)alloc(256 * 256 * 2);
    u16* Wto = (u16*)alloc(256 * 256 * 2);
    u16* Qh  = (u16*)alloc(MN * 256 * 2);
    u16* Kh  = (u16*)alloc(MN * 256 * 2);
    u16* Vh  = (u16*)alloc(MN * 256 * 2);
    u16* AVb = (u16*)alloc(MN * 256 * 2);

    wprep<<<dim3(4, 4, 4), 256, 0, stream>>>(Wq, Wk, Wv, Wo, Wtq, Wtk, Wtv, Wto);
    gemm_proj<<<dim3(128, 2, 3), 256, 0, stream>>>(Q, K, Wtq, Wtk, Wtv,
                                                   bq, bk, bv, Qh, Kh, Vh);
    attn<<<dim3(4096), 256, 0, stream>>>(Qh, Kh, Vh, nbr, AVb);
    gemm_out<<<dim3(256, 2), 256, 0, stream>>>(AVb, Wto, bo, out);
}